// Round 13
// baseline (1140.591 us; speedup 1.0000x reference)
//
#include <hip/hip_runtime.h>
#include <hip/hip_bf16.h>

#define BB 2
#define TT 12
#define NN 20000
#define FF 9
#define HH 64
#define EE 200000

typedef __hip_bfloat16 bf;
typedef __attribute__((ext_vector_type(8))) short s8v;   // 8 bf16 (4 VGPRs)
typedef __attribute__((ext_vector_type(4))) float f4v;

// ---- big buffers: all-timestep activations (static device globals) -------
__device__ unsigned g_p [TT*NN*HH];   // 61.4 MB  P = X@W1l (bf16 pair)
__device__ float2   g_q [TT*NN*HH];   // 122.9 MB Q = X@W1r + b1 (fp32 pair)
__device__ unsigned g_xa[TT*NN*HH];   // 61.4 MB  conv1 out
__device__ unsigned g_ag[TT*NN*HH];   // 61.4 MB  aggregation scratch
__device__ unsigned g_xb[TT*NN*HH];   // 61.4 MB  conv2 out
__device__ float2   g_x9[TT*NN*FF];   // 17.3 MB  conv3 out
__device__ float    g_gi[TT*27*BB*NN];// 51.8 MB  gi = x@Wih+bih
__device__ int      g_rp[NN+1];
__device__ int      g_cnt[NN];
__device__ int      g_csrc[EE];
__device__ float    g_cw[EE];
__device__ float    g_cvec[32];

__device__ __forceinline__ float lo2f(unsigned u){ unsigned v=u<<16; float f; __builtin_memcpy(&f,&v,4); return f; }
__device__ __forceinline__ float hi2f(unsigned u){ unsigned v=u&0xffff0000u; float f; __builtin_memcpy(&f,&v,4); return f; }
__device__ __forceinline__ unsigned short f2us(float f){ bf h=__float2bfloat16(f); unsigned short u; __builtin_memcpy(&u,&h,2); return u; }
__device__ __forceinline__ unsigned pack2(float a0, float a1){ return (unsigned)f2us(a0) | ((unsigned)f2us(a1)<<16); }
__device__ __forceinline__ float elu(float x){ return x>0.f ? x : expm1f(x); }

// ---- CSR build -----------------------------------------------------------
__global__ void k_zero(){
  int i = blockIdx.x*256 + threadIdx.x;
  if(i < NN) g_cnt[i] = 0;
}
__global__ void k_count(const int* __restrict__ dst){
  int e = blockIdx.x*256 + threadIdx.x;
  if(e < EE) atomicAdd(&g_cnt[dst[e]], 1);
}
__global__ void k_scan(){
  __shared__ int part[256];
  const int CH = 79;
  int t = threadIdx.x;
  int base = t*CH;
  int s = 0;
  for(int i=0;i<CH;i++){ int idx=base+i; if(idx<NN) s += g_cnt[idx]; }
  part[t] = s; __syncthreads();
  for(int off=1; off<256; off<<=1){
    int v = (t>=off) ? part[t-off] : 0;
    __syncthreads();
    part[t] += v;
    __syncthreads();
  }
  int run = (t==0) ? 0 : part[t-1];
  for(int i=0;i<CH;i++){
    int idx=base+i;
    if(idx<NN){ run += g_cnt[idx]; g_rp[idx+1] = run; }
  }
  if(t==0) g_rp[0] = 0;
}
__global__ void k_fill(const int* __restrict__ dst, const int* __restrict__ src,
                       const float* __restrict__ ew){
  int e = blockIdx.x*256 + threadIdx.x;
  if(e >= EE) return;
  int d = dst[e];
  int pos = g_rp[d] + atomicAdd(&g_cnt[d], 1);
  g_csrc[pos] = src[e];
  g_cw[pos]   = ew[e];
}

// ---- head precompute -----------------------------------------------------
__global__ void k_head(const float* __restrict__ encW, const float* __restrict__ encb,
                       const float* __restrict__ decW, const float* __restrict__ decb,
                       const float* __restrict__ te){
  __shared__ float c[19];
  int tid = threadIdx.x;
  if(tid < 18){ float s=0.f; for(int j=0;j<64;j++) s += encW[tid*64+j]*decW[j]; c[tid]=s; }
  if(tid == 18){ float s=decb[0]; for(int j=0;j<64;j++) s += encb[j]*decW[j]; c[18]=s; }
  __syncthreads();
  if(tid < FF) g_cvec[tid] = c[tid];
  if(tid < BB){ float s=c[18]; for(int k=0;k<FF;k++) s += te[tid*FF+k]*c[9+k]; g_cvec[FF+tid]=s; }
}

// ---- gemm1 (all t): P = X@W1l (bf16 pair), Q = X@W1r + b1 (fp32 pair) ---
__global__ __launch_bounds__(256) void k_gemm1_all(const float* __restrict__ g,
                                                   const float* __restrict__ Wl,
                                                   const float* __restrict__ bias,
                                                   const float* __restrict__ Wr){
  int t = blockIdx.y;
  __shared__ float sWl[FF*HH], sWr[FF*HH], sb[HH];
  int tid = threadIdx.x;
  for(int i=tid;i<FF*HH;i+=256){ sWl[i]=Wl[t*FF*HH+i]; sWr[i]=Wr[t*FF*HH+i]; }
  if(tid<HH) sb[tid]=bias[t*HH+tid];
  __syncthreads();
  int lane = tid & 63, wave = tid >> 6;
  int quad = lane >> 4, col = lane & 15;
  int base16 = blockIdx.x*64 + wave*16;
  if(base16 >= NN) return;
  size_t tb = (size_t)t*NN;
  int nodeA = base16 + col;
  long gb0 = ((long)(0*TT+t)*NN + nodeA)*FF;
  long gb1 = ((long)(1*TT+t)*NN + nodeA)*FF;
  s8v A0, A1;
  #pragma unroll
  for(int j=0;j<8;j++){
    int k = quad*8 + j;
    A0[j] = (k<FF) ? (short)f2us(g[gb0 + k]) : (short)0;
    A1[j] = (k<FF) ? (short)f2us(g[gb1 + k]) : (short)0;
  }
  #pragma unroll
  for(int nt=0; nt<8; nt++){
    int oc = (nt & 3)*16 + col;
    s8v B;
    #pragma unroll
    for(int j=0;j<8;j++){
      int k = quad*8 + j;
      float wv = 0.f;
      if(k < FF) wv = (nt < 4) ? sWl[k*HH + oc] : sWr[k*HH + oc];
      B[j] = (short)f2us(wv);
    }
    f4v c0 = {0.f,0.f,0.f,0.f}, c1 = {0.f,0.f,0.f,0.f};
    c0 = __builtin_amdgcn_mfma_f32_16x16x32_bf16(A0, B, c0, 0, 0, 0);
    c1 = __builtin_amdgcn_mfma_f32_16x16x32_bf16(A1, B, c1, 0, 0, 0);
    #pragma unroll
    for(int reg=0; reg<4; reg++){
      int node = base16 + quad*4 + reg;
      if(nt < 4){
        g_p[(tb+node)*HH + oc] = pack2(c0[reg], c1[reg]);
      }else{
        float bn = sb[oc];
        float2 o; o.x = c0[reg]+bn; o.y = c1[reg]+bn;
        g_q[(tb+node)*HH + oc] = o;
      }
    }
  }
}

// ---- XCD-tiled aggregation -----------------------------------------------
// 24 tiles = (t, half-row 128B). Tile p -> XCD class p%8 via blockIdx%8.
// 8 lanes/edge (sub = lane&7), 8 edges per wave-instruction (grp = lane>>3).
// EPI=0: plain agg/deg -> g_ag.  EPI=1: ELU(agg/deg + Q) -> g_xa (from g_p).
template<int EPI>
__global__ void k_aggx(const unsigned* __restrict__ src, unsigned* __restrict__ dstb){
  int tid = threadIdx.x;
  int lane = tid & 63;
  int grp  = lane >> 3;                  // edge group 0..7
  int sub  = lane & 7;                   // 16-B chunk within 128B half
  int cls  = blockIdx.x & 7;             // XCD class
  int wid  = ((blockIdx.x>>3)<<2) + (tid>>6);   // wave id within class: 0..1023
  #pragma unroll
  for(int pp=0; pp<3; pp++){
    int pair = cls + 8*pp;               // 0..23
    int t = pair >> 1, half = pair & 1;
    size_t tb = (size_t)t*NN;
    int hb = half*32;                    // u32 offset of half-row
    for(int n=wid; n<NN; n+=1024){
      int r0=g_rp[n], r1=g_rp[n+1];
      float dg = fmaxf((float)(r1-r0), 1.f);
      float p0[4]={0.f,0.f,0.f,0.f}, p1[4]={0.f,0.f,0.f,0.f};
      for(int base=r0; base<r1; base+=64){
        int cnt = min(64, r1-base);
        int ms = 0; float mw = 0.f;
        if(lane < cnt){ ms = g_csrc[base+lane]; mw = g_cw[base+lane]; }
        for(int k=0;k<cnt;k+=8){
          int   sg = __shfl(ms, k+grp, 64);
          float wg = __shfl(mw, k+grp, 64);
          const uint4 v = *reinterpret_cast<const uint4*>(src + (tb+(size_t)sg)*HH + hb + (sub<<2));
          p0[0]+=wg*lo2f(v.x); p1[0]+=wg*hi2f(v.x);
          p0[1]+=wg*lo2f(v.y); p1[1]+=wg*hi2f(v.y);
          p0[2]+=wg*lo2f(v.z); p1[2]+=wg*hi2f(v.z);
          p0[3]+=wg*lo2f(v.w); p1[3]+=wg*hi2f(v.w);
        }
      }
      #pragma unroll
      for(int q=0;q<4;q++){
        p0[q] += __shfl_xor(p0[q], 8,64); p1[q] += __shfl_xor(p1[q], 8,64);
        p0[q] += __shfl_xor(p0[q],16,64); p1[q] += __shfl_xor(p1[q],16,64);
        p0[q] += __shfl_xor(p0[q],32,64); p1[q] += __shfl_xor(p1[q],32,64);
      }
      if(lane < 8){
        uint4 o;
        if(EPI){
          const float2* qr = g_q + (tb+n)*HH + hb + (lane<<2);
          float2 q0=qr[0], q1=qr[1], q2=qr[2], q3=qr[3];
          o.x = pack2(elu(p0[0]/dg + q0.x), elu(p1[0]/dg + q0.y));
          o.y = pack2(elu(p0[1]/dg + q1.x), elu(p1[1]/dg + q1.y));
          o.z = pack2(elu(p0[2]/dg + q2.x), elu(p1[2]/dg + q2.y));
          o.w = pack2(elu(p0[3]/dg + q3.x), elu(p1[3]/dg + q3.y));
        }else{
          o.x = pack2(p0[0]/dg, p1[0]/dg);
          o.y = pack2(p0[1]/dg, p1[1]/dg);
          o.z = pack2(p0[2]/dg, p1[2]/dg);
          o.w = pack2(p0[3]/dg, p1[3]/dg);
        }
        *reinterpret_cast<uint4*>(dstb + (tb+(size_t)n)*HH + hb + (lane<<2)) = o;
      }
    }
  }
}

// ---- conv2 GEMM (all t): ELU([AGG|X]@[Wl;Wr]+b), MFMA ------------------
__global__ __launch_bounds__(256) void k_gemm2_all(const float* __restrict__ Wl,
                                                   const float* __restrict__ bias,
                                                   const float* __restrict__ Wr){
  int t = blockIdx.y;
  __shared__ float sW[128*65];
  int tid = threadIdx.x;
  for(int i=tid; i<64*64; i+=256){
    int r = i >> 6, c = i & 63;
    sW[r*65+c]      = Wl[(size_t)t*4096 + i];
    sW[(r+64)*65+c] = Wr[(size_t)t*4096 + i];
  }
  __syncthreads();
  int lane = tid & 63, wave = tid >> 6;
  int quad = lane >> 4, col = lane & 15;
  int base16 = blockIdx.x*64 + wave*16;
  if(base16 >= NN) return;
  size_t tb = (size_t)t*NN;
  int nodeA = base16 + col;
  s8v A0[4], A1[4];
  #pragma unroll
  for(int ks=0; ks<4; ks++){
    const unsigned* srcb = (ks < 2) ? g_ag : g_xa;
    int koff = (ks & 1)*32 + quad*8;
    const uint4 u = *reinterpret_cast<const uint4*>(srcb + (tb+nodeA)*HH + koff);
    const uint4 v = *reinterpret_cast<const uint4*>(srcb + (tb+nodeA)*HH + koff + 4);
    unsigned uu[8] = {u.x,u.y,u.z,u.w,v.x,v.y,v.z,v.w};
    #pragma unroll
    for(int j=0;j<8;j++){
      A0[ks][j] = (short)(uu[j] & 0xffffu);
      A1[ks][j] = (short)(uu[j] >> 16);
    }
  }
  #pragma unroll
  for(int nt=0; nt<4; nt++){
    f4v c0 = {0.f,0.f,0.f,0.f}, c1 = {0.f,0.f,0.f,0.f};
    #pragma unroll
    for(int ks=0; ks<4; ks++){
      s8v B;
      #pragma unroll
      for(int j=0;j<8;j++)
        B[j] = (short)f2us(sW[(ks*32+quad*8+j)*65 + nt*16+col]);
      c0 = __builtin_amdgcn_mfma_f32_16x16x32_bf16(A0[ks], B, c0, 0, 0, 0);
      c1 = __builtin_amdgcn_mfma_f32_16x16x32_bf16(A1[ks], B, c1, 0, 0, 0);
    }
    float bn = bias[t*HH + nt*16 + col];
    #pragma unroll
    for(int reg=0; reg<4; reg++){
      int node = base16 + quad*4 + reg;
      g_xb[(tb+node)*HH + nt*16 + col] = pack2(elu(c0[reg]+bn), elu(c1[reg]+bn));
    }
  }
}

// ---- conv3 GEMM (all t) -> g_x9 (fp32x2) --------------------------------
__global__ __launch_bounds__(256) void k_gemm3_all(const float* __restrict__ Wl,
                                                   const float* __restrict__ bias,
                                                   const float* __restrict__ Wr){
  int t = blockIdx.y;
  __shared__ float sW[128*10];
  int tid = threadIdx.x;
  for(int i=tid; i<64*FF; i+=256){
    int r = i/FF, c = i - r*FF;
    sW[r*10+c]      = Wl[(size_t)t*HH*FF + i];
    sW[(r+64)*10+c] = Wr[(size_t)t*HH*FF + i];
  }
  __syncthreads();
  int lane = tid & 63, wave = tid >> 6;
  int quad = lane >> 4, col = lane & 15;
  int base16 = blockIdx.x*64 + wave*16;
  if(base16 >= NN) return;
  size_t tb = (size_t)t*NN;
  int nodeA = base16 + col;
  f4v c0 = {0.f,0.f,0.f,0.f}, c1 = {0.f,0.f,0.f,0.f};
  #pragma unroll
  for(int ks=0; ks<4; ks++){
    const unsigned* srcb = (ks < 2) ? g_ag : g_xb;
    int koff = (ks & 1)*32 + quad*8;
    const uint4 u = *reinterpret_cast<const uint4*>(srcb + (tb+nodeA)*HH + koff);
    const uint4 v = *reinterpret_cast<const uint4*>(srcb + (tb+nodeA)*HH + koff + 4);
    unsigned uu[8] = {u.x,u.y,u.z,u.w,v.x,v.y,v.z,v.w};
    s8v A0, A1, B;
    #pragma unroll
    for(int j=0;j<8;j++){
      A0[j] = (short)(uu[j] & 0xffffu);
      A1[j] = (short)(uu[j] >> 16);
      B[j]  = (col < FF) ? (short)f2us(sW[(ks*32+quad*8+j)*10 + col]) : (short)0;
    }
    c0 = __builtin_amdgcn_mfma_f32_16x16x32_bf16(A0, B, c0, 0, 0, 0);
    c1 = __builtin_amdgcn_mfma_f32_16x16x32_bf16(A1, B, c1, 0, 0, 0);
  }
  if(col < FF){
    float bn = bias[t*FF + col];
    #pragma unroll
    for(int reg=0; reg<4; reg++){
      int node = base16 + quad*4 + reg;
      float2 o; o.x = elu(c0[reg]+bn); o.y = elu(c1[reg]+bn);
      g_x9[(tb+node)*FF + col] = o;
    }
  }
}

// ---- k_gix: gi = x@Wih + bih for all t (parallel; scalar weights) -------
__global__ void k_gix(const float* __restrict__ Wih, const float* __restrict__ bih){
  int t = blockIdx.y;
  int n = blockIdx.x*256 + threadIdx.x;
  if(n >= NN) return;
  float x0[FF], x1[FF];
  #pragma unroll
  for(int f=0;f<FF;f++){
    float2 p = g_x9[((size_t)t*NN+n)*FF+f];
    x0[f] = p.x; x1[f] = p.y;
  }
  #pragma unroll
  for(int j=0;j<27;j++){
    float bi = bih[t*27+j];
    float a0 = bi, a1 = bi;
    #pragma unroll
    for(int i=0;i<FF;i++){
      float w = Wih[t*243 + i*27 + j];
      a0 += x0[i]*w; a1 += x1[i]*w;
    }
    size_t base = ((size_t)(t*27+j)*BB)*NN + n;
    g_gi[base]      = a0;
    g_gi[base + NN] = a1;
  }
}

// ---- k_gru_seq: h-recurrence only; scalar weights, no LDS ---------------
__global__ void k_gru_seq(const float* __restrict__ g, const float* __restrict__ Whh,
                          const float* __restrict__ bhh, float* __restrict__ out){
  int id = blockIdx.x*128 + threadIdx.x;
  if(id >= BB*NN) return;
  int b = id / NN, n = id - b*NN;
  float c9[FF];
  #pragma unroll
  for(int f=0;f<FF;f++) c9[f] = g_cvec[f];
  float cb = g_cvec[FF+b];
  float h[FF];
  #pragma unroll
  for(int f=0;f<FF;f++) h[f] = 0.f;
  for(int t=0;t<TT;t++){
    float gh[27];
    #pragma unroll
    for(int j=0;j<27;j++) gh[j] = bhh[t*27+j];
    #pragma unroll
    for(int i=0;i<FF;i++){
      float hi = h[i];
      #pragma unroll
      for(int j=0;j<27;j++) gh[j] += hi * Whh[t*243 + i*27 + j];
    }
    float gi[27];
    #pragma unroll
    for(int j=0;j<27;j++)
      gi[j] = g_gi[((size_t)(t*27+j)*BB + b)*NN + n];
    float acc = cb;
    #pragma unroll
    for(int f=0;f<FF;f++){
      float r = 1.f/(1.f+__expf(-(gi[f]+gh[f])));
      float z = 1.f/(1.f+__expf(-(gi[9+f]+gh[9+f])));
      float nv = tanhf(gi[18+f] + r*gh[18+f]);
      h[f] = (1.f-z)*nv + z*h[f];
      acc += h[f]*c9[f];
    }
    size_t gidx = (size_t)(b*TT+t)*NN + n;
    float m = (g[gidx*FF] != 0.f) ? 1.f : 0.f;
    out[gidx] = acc*m;
  }
}

extern "C" void kernel_launch(void* const* d_in, const int* in_sizes, int n_in,
                              void* d_out, int out_size, void* d_ws, size_t ws_size,
                              hipStream_t stream){
  const float* g    = (const float*)d_in[0];
  const float* te   = (const float*)d_in[1];
  const float* ew   = (const float*)d_in[3];
  const int* esrc = (const int*)d_in[4];
  const int* edst = (const int*)d_in[5];
  const float* W1l=(const float*)d_in[6];  const float* b1 =(const float*)d_in[7];  const float* W1r=(const float*)d_in[8];
  const float* W2l=(const float*)d_in[9];  const float* b2 =(const float*)d_in[10]; const float* W2r=(const float*)d_in[11];
  const float* W3l=(const float*)d_in[12]; const float* b3 =(const float*)d_in[13]; const float* W3r=(const float*)d_in[14];
  const float* Wih=(const float*)d_in[15]; const float* Whh=(const float*)d_in[16];
  const float* bih=(const float*)d_in[17]; const float* bhh=(const float*)d_in[18];
  const float* encW=(const float*)d_in[19]; const float* encb=(const float*)d_in[20];
  const float* decW=(const float*)d_in[21]; const float* decb=(const float*)d_in[22];
  float* out = (float*)d_out;

  k_zero <<<(NN+255)/256, 256, 0, stream>>>();
  k_count<<<(EE+255)/256, 256, 0, stream>>>(edst);
  k_scan <<<1, 256, 0, stream>>>();
  k_zero <<<(NN+255)/256, 256, 0, stream>>>();
  k_fill <<<(EE+255)/256, 256, 0, stream>>>(edst, esrc, ew);
  k_head <<<1, 64, 0, stream>>>(encW, encb, decW, decb, te);

  // device-global pointers for k_aggx args
  unsigned *p_p, *p_xa, *p_ag, *p_xb;
  hipGetSymbolAddress((void**)&p_p,  HIP_SYMBOL(g_p));
  hipGetSymbolAddress((void**)&p_xa, HIP_SYMBOL(g_xa));
  hipGetSymbolAddress((void**)&p_ag, HIP_SYMBOL(g_ag));
  hipGetSymbolAddress((void**)&p_xb, HIP_SYMBOL(g_xb));

  dim3 ggm((NN+63)/64, TT);
  dim3 ggi((NN+255)/256, TT);
  k_gemm1_all<<<ggm, 256, 0, stream>>>(g, W1l, b1, W1r);
  k_aggx<1><<<2048, 256, 0, stream>>>(p_p, p_xa);    // xa = ELU(agg(P)/deg + Q)
  k_aggx<0><<<2048, 256, 0, stream>>>(p_xa, p_ag);   // ag = agg(xa)/deg
  k_gemm2_all<<<ggm, 256, 0, stream>>>(W2l, b2, W2r);
  k_aggx<0><<<2048, 256, 0, stream>>>(p_xb, p_ag);   // ag = agg(xb)/deg
  k_gemm3_all<<<ggm, 256, 0, stream>>>(W3l, b3, W3r);
  k_gix<<<ggi, 256, 0, stream>>>(Wih, bih);
  k_gru_seq<<<(BB*NN+127)/128, 128, 0, stream>>>(g, Whh, bhh, out);
}

// Round 14
// 808.078 us; speedup vs baseline: 1.4115x; 1.4115x over previous
//
#include <hip/hip_runtime.h>
#include <hip/hip_bf16.h>

#define BB 2
#define TT 12
#define NN 20000
#define FF 9
#define HH 64
#define EE 200000

typedef __hip_bfloat16 bf;
typedef __attribute__((ext_vector_type(8))) short s8v;   // 8 bf16 (4 VGPRs)
typedef __attribute__((ext_vector_type(4))) float f4v;

// ---- big buffers: all-timestep activations (static device globals) -------
__device__ unsigned g_p [TT*NN*HH];   // 61.4 MB  P = X@W1l (bf16 pair)
__device__ float2   g_q [TT*NN*HH];   // 122.9 MB Q = X@W1r + b1 (fp32 pair)
__device__ unsigned g_xa[TT*NN*HH];   // 61.4 MB  conv1 out
__device__ unsigned g_ag[TT*NN*HH];   // 61.4 MB  aggregation scratch
__device__ unsigned g_xb[TT*NN*HH];   // 61.4 MB  conv2 out
__device__ float2   g_x9[TT*NN*FF];   // 17.3 MB  conv3 out
__device__ float    g_gi[TT*27*BB*NN];// 51.8 MB  gi = x@Wih+bih
__device__ int      g_rp[NN+1];
__device__ int      g_cnt[NN];
__device__ int      g_csrc[EE];
__device__ float    g_cw[EE];
__device__ float    g_cvec[32];

__device__ __forceinline__ float lo2f(unsigned u){ unsigned v=u<<16; float f; __builtin_memcpy(&f,&v,4); return f; }
__device__ __forceinline__ float hi2f(unsigned u){ unsigned v=u&0xffff0000u; float f; __builtin_memcpy(&f,&v,4); return f; }
__device__ __forceinline__ unsigned short f2us(float f){ bf h=__float2bfloat16(f); unsigned short u; __builtin_memcpy(&u,&h,2); return u; }
__device__ __forceinline__ unsigned pack2(float a0, float a1){ return (unsigned)f2us(a0) | ((unsigned)f2us(a1)<<16); }
__device__ __forceinline__ float elu(float x){ return x>0.f ? x : expm1f(x); }

// ---- CSR build -----------------------------------------------------------
__global__ void k_zero(){
  int i = blockIdx.x*256 + threadIdx.x;
  if(i < NN) g_cnt[i] = 0;
}
__global__ void k_count(const int* __restrict__ dst){
  int e = blockIdx.x*256 + threadIdx.x;
  if(e < EE) atomicAdd(&g_cnt[dst[e]], 1);
}
__global__ void k_scan(){
  __shared__ int part[256];
  const int CH = 79;
  int t = threadIdx.x;
  int base = t*CH;
  int s = 0;
  for(int i=0;i<CH;i++){ int idx=base+i; if(idx<NN) s += g_cnt[idx]; }
  part[t] = s; __syncthreads();
  for(int off=1; off<256; off<<=1){
    int v = (t>=off) ? part[t-off] : 0;
    __syncthreads();
    part[t] += v;
    __syncthreads();
  }
  int run = (t==0) ? 0 : part[t-1];
  for(int i=0;i<CH;i++){
    int idx=base+i;
    if(idx<NN){ run += g_cnt[idx]; g_rp[idx+1] = run; }
  }
  if(t==0) g_rp[0] = 0;
}
__global__ void k_fill(const int* __restrict__ dst, const int* __restrict__ src,
                       const float* __restrict__ ew){
  int e = blockIdx.x*256 + threadIdx.x;
  if(e >= EE) return;
  int d = dst[e];
  int pos = g_rp[d] + atomicAdd(&g_cnt[d], 1);
  g_csrc[pos] = src[e];
  g_cw[pos]   = ew[e];
}

// ---- head precompute -----------------------------------------------------
__global__ void k_head(const float* __restrict__ encW, const float* __restrict__ encb,
                       const float* __restrict__ decW, const float* __restrict__ decb,
                       const float* __restrict__ te){
  __shared__ float c[19];
  int tid = threadIdx.x;
  if(tid < 18){ float s=0.f; for(int j=0;j<64;j++) s += encW[tid*64+j]*decW[j]; c[tid]=s; }
  if(tid == 18){ float s=decb[0]; for(int j=0;j<64;j++) s += encb[j]*decW[j]; c[18]=s; }
  __syncthreads();
  if(tid < FF) g_cvec[tid] = c[tid];
  if(tid < BB){ float s=c[18]; for(int k=0;k<FF;k++) s += te[tid*FF+k]*c[9+k]; g_cvec[FF+tid]=s; }
}

// ---- gemm1 (all t): P = X@W1l (bf16 pair), Q = X@W1r + b1 (fp32 pair) ---
__global__ __launch_bounds__(256) void k_gemm1_all(const float* __restrict__ g,
                                                   const float* __restrict__ Wl,
                                                   const float* __restrict__ bias,
                                                   const float* __restrict__ Wr){
  int t = blockIdx.y;
  __shared__ float sWl[FF*HH], sWr[FF*HH], sb[HH];
  int tid = threadIdx.x;
  for(int i=tid;i<FF*HH;i+=256){ sWl[i]=Wl[t*FF*HH+i]; sWr[i]=Wr[t*FF*HH+i]; }
  if(tid<HH) sb[tid]=bias[t*HH+tid];
  __syncthreads();
  int lane = tid & 63, wave = tid >> 6;
  int quad = lane >> 4, col = lane & 15;
  int base16 = blockIdx.x*64 + wave*16;
  if(base16 >= NN) return;
  size_t tb = (size_t)t*NN;
  int nodeA = base16 + col;
  long gb0 = ((long)(0*TT+t)*NN + nodeA)*FF;
  long gb1 = ((long)(1*TT+t)*NN + nodeA)*FF;
  s8v A0, A1;
  #pragma unroll
  for(int j=0;j<8;j++){
    int k = quad*8 + j;
    A0[j] = (k<FF) ? (short)f2us(g[gb0 + k]) : (short)0;
    A1[j] = (k<FF) ? (short)f2us(g[gb1 + k]) : (short)0;
  }
  #pragma unroll
  for(int nt=0; nt<8; nt++){
    int oc = (nt & 3)*16 + col;
    s8v B;
    #pragma unroll
    for(int j=0;j<8;j++){
      int k = quad*8 + j;
      float wv = 0.f;
      if(k < FF) wv = (nt < 4) ? sWl[k*HH + oc] : sWr[k*HH + oc];
      B[j] = (short)f2us(wv);
    }
    f4v c0 = {0.f,0.f,0.f,0.f}, c1 = {0.f,0.f,0.f,0.f};
    c0 = __builtin_amdgcn_mfma_f32_16x16x32_bf16(A0, B, c0, 0, 0, 0);
    c1 = __builtin_amdgcn_mfma_f32_16x16x32_bf16(A1, B, c1, 0, 0, 0);
    #pragma unroll
    for(int reg=0; reg<4; reg++){
      int node = base16 + quad*4 + reg;
      if(nt < 4){
        g_p[(tb+node)*HH + oc] = pack2(c0[reg], c1[reg]);
      }else{
        float bn = sb[oc];
        float2 o; o.x = c0[reg]+bn; o.y = c1[reg]+bn;
        g_q[(tb+node)*HH + oc] = o;
      }
    }
  }
}

// ---- t-major sliding-window aggregation ----------------------------------
// t = blockIdx.y (slow dispatch axis): at ~1024 resident blocks, roughly one
// 5.12 MB t-slice is the active gather target -> L2 captures deg-10 reuse.
// EPI=0: ag = agg(src)/deg.  EPI=1: xa = ELU(agg(src)/deg + Q).
template<int EPI>
__global__ void k_aggt(const unsigned* __restrict__ src, unsigned* __restrict__ dstb){
  int t = blockIdx.y;
  size_t tb = (size_t)t*NN;
  int tid = threadIdx.x;
  int lane = tid & 63;
  int grp  = lane >> 4;                  // edge group 0..3
  int sub  = lane & 15;                  // 16-B chunk within 256B row
  int wid  = (blockIdx.x<<2) + (tid>>6); // 0..4095
  for(int n=wid; n<NN; n+=4096){
    int r0=g_rp[n], r1=g_rp[n+1];
    float dg = fmaxf((float)(r1-r0), 1.f);
    float p0[4]={0.f,0.f,0.f,0.f}, p1[4]={0.f,0.f,0.f,0.f};
    for(int base=r0; base<r1; base+=64){
      int cnt = min(64, r1-base);
      int ms = 0; float mw = 0.f;
      if(lane < cnt){ ms = g_csrc[base+lane]; mw = g_cw[base+lane]; }
      for(int k=0;k<cnt;k+=4){
        int   sg = __shfl(ms, k+grp, 64);
        float wg = __shfl(mw, k+grp, 64);
        const uint4 v = *reinterpret_cast<const uint4*>(src + (tb+(size_t)sg)*HH + (sub<<2));
        p0[0]+=wg*lo2f(v.x); p1[0]+=wg*hi2f(v.x);
        p0[1]+=wg*lo2f(v.y); p1[1]+=wg*hi2f(v.y);
        p0[2]+=wg*lo2f(v.z); p1[2]+=wg*hi2f(v.z);
        p0[3]+=wg*lo2f(v.w); p1[3]+=wg*hi2f(v.w);
      }
    }
    #pragma unroll
    for(int q=0;q<4;q++){
      p0[q] += __shfl_xor(p0[q],16,64); p1[q] += __shfl_xor(p1[q],16,64);
      p0[q] += __shfl_xor(p0[q],32,64); p1[q] += __shfl_xor(p1[q],32,64);
    }
    if(lane < 16){
      uint4 o;
      if(EPI){
        const float2* qr = g_q + (tb+(size_t)n)*HH + (lane<<2);
        float2 q0=qr[0], q1=qr[1], q2=qr[2], q3=qr[3];
        o.x = pack2(elu(p0[0]/dg + q0.x), elu(p1[0]/dg + q0.y));
        o.y = pack2(elu(p0[1]/dg + q1.x), elu(p1[1]/dg + q1.y));
        o.z = pack2(elu(p0[2]/dg + q2.x), elu(p1[2]/dg + q2.y));
        o.w = pack2(elu(p0[3]/dg + q3.x), elu(p1[3]/dg + q3.y));
      }else{
        o.x = pack2(p0[0]/dg, p1[0]/dg);
        o.y = pack2(p0[1]/dg, p1[1]/dg);
        o.z = pack2(p0[2]/dg, p1[2]/dg);
        o.w = pack2(p0[3]/dg, p1[3]/dg);
      }
      *reinterpret_cast<uint4*>(dstb + (tb+(size_t)n)*HH + (lane<<2)) = o;
    }
  }
}

// ---- conv2 GEMM (all t): ELU([AGG|X]@[Wl;Wr]+b), MFMA ------------------
__global__ __launch_bounds__(256) void k_gemm2_all(const float* __restrict__ Wl,
                                                   const float* __restrict__ bias,
                                                   const float* __restrict__ Wr){
  int t = blockIdx.y;
  __shared__ float sW[128*65];
  int tid = threadIdx.x;
  for(int i=tid; i<64*64; i+=256){
    int r = i >> 6, c = i & 63;
    sW[r*65+c]      = Wl[(size_t)t*4096 + i];
    sW[(r+64)*65+c] = Wr[(size_t)t*4096 + i];
  }
  __syncthreads();
  int lane = tid & 63, wave = tid >> 6;
  int quad = lane >> 4, col = lane & 15;
  int base16 = blockIdx.x*64 + wave*16;
  if(base16 >= NN) return;
  size_t tb = (size_t)t*NN;
  int nodeA = base16 + col;
  s8v A0[4], A1[4];
  #pragma unroll
  for(int ks=0; ks<4; ks++){
    const unsigned* srcb = (ks < 2) ? g_ag : g_xa;
    int koff = (ks & 1)*32 + quad*8;
    const uint4 u = *reinterpret_cast<const uint4*>(srcb + (tb+nodeA)*HH + koff);
    const uint4 v = *reinterpret_cast<const uint4*>(srcb + (tb+nodeA)*HH + koff + 4);
    unsigned uu[8] = {u.x,u.y,u.z,u.w,v.x,v.y,v.z,v.w};
    #pragma unroll
    for(int j=0;j<8;j++){
      A0[ks][j] = (short)(uu[j] & 0xffffu);
      A1[ks][j] = (short)(uu[j] >> 16);
    }
  }
  #pragma unroll
  for(int nt=0; nt<4; nt++){
    f4v c0 = {0.f,0.f,0.f,0.f}, c1 = {0.f,0.f,0.f,0.f};
    #pragma unroll
    for(int ks=0; ks<4; ks++){
      s8v B;
      #pragma unroll
      for(int j=0;j<8;j++)
        B[j] = (short)f2us(sW[(ks*32+quad*8+j)*65 + nt*16+col]);
      c0 = __builtin_amdgcn_mfma_f32_16x16x32_bf16(A0[ks], B, c0, 0, 0, 0);
      c1 = __builtin_amdgcn_mfma_f32_16x16x32_bf16(A1[ks], B, c1, 0, 0, 0);
    }
    float bn = bias[t*HH + nt*16 + col];
    #pragma unroll
    for(int reg=0; reg<4; reg++){
      int node = base16 + quad*4 + reg;
      g_xb[(tb+node)*HH + nt*16 + col] = pack2(elu(c0[reg]+bn), elu(c1[reg]+bn));
    }
  }
}

// ---- conv3 GEMM (all t) -> g_x9 (fp32x2) --------------------------------
__global__ __launch_bounds__(256) void k_gemm3_all(const float* __restrict__ Wl,
                                                   const float* __restrict__ bias,
                                                   const float* __restrict__ Wr){
  int t = blockIdx.y;
  __shared__ float sW[128*10];
  int tid = threadIdx.x;
  for(int i=tid; i<64*FF; i+=256){
    int r = i/FF, c = i - r*FF;
    sW[r*10+c]      = Wl[(size_t)t*HH*FF + i];
    sW[(r+64)*10+c] = Wr[(size_t)t*HH*FF + i];
  }
  __syncthreads();
  int lane = tid & 63, wave = tid >> 6;
  int quad = lane >> 4, col = lane & 15;
  int base16 = blockIdx.x*64 + wave*16;
  if(base16 >= NN) return;
  size_t tb = (size_t)t*NN;
  int nodeA = base16 + col;
  f4v c0 = {0.f,0.f,0.f,0.f}, c1 = {0.f,0.f,0.f,0.f};
  #pragma unroll
  for(int ks=0; ks<4; ks++){
    const unsigned* srcb = (ks < 2) ? g_ag : g_xb;
    int koff = (ks & 1)*32 + quad*8;
    const uint4 u = *reinterpret_cast<const uint4*>(srcb + (tb+nodeA)*HH + koff);
    const uint4 v = *reinterpret_cast<const uint4*>(srcb + (tb+nodeA)*HH + koff + 4);
    unsigned uu[8] = {u.x,u.y,u.z,u.w,v.x,v.y,v.z,v.w};
    s8v A0, A1, B;
    #pragma unroll
    for(int j=0;j<8;j++){
      A0[j] = (short)(uu[j] & 0xffffu);
      A1[j] = (short)(uu[j] >> 16);
      B[j]  = (col < FF) ? (short)f2us(sW[(ks*32+quad*8+j)*10 + col]) : (short)0;
    }
    c0 = __builtin_amdgcn_mfma_f32_16x16x32_bf16(A0, B, c0, 0, 0, 0);
    c1 = __builtin_amdgcn_mfma_f32_16x16x32_bf16(A1, B, c1, 0, 0, 0);
  }
  if(col < FF){
    float bn = bias[t*FF + col];
    #pragma unroll
    for(int reg=0; reg<4; reg++){
      int node = base16 + quad*4 + reg;
      float2 o; o.x = elu(c0[reg]+bn); o.y = elu(c1[reg]+bn);
      g_x9[(tb+node)*FF + col] = o;
    }
  }
}

// ---- k_gix: gi = x@Wih + bih for all t (parallel; scalar weights) -------
__global__ void k_gix(const float* __restrict__ Wih, const float* __restrict__ bih){
  int t = blockIdx.y;
  int n = blockIdx.x*256 + threadIdx.x;
  if(n >= NN) return;
  float x0[FF], x1[FF];
  #pragma unroll
  for(int f=0;f<FF;f++){
    float2 p = g_x9[((size_t)t*NN+n)*FF+f];
    x0[f] = p.x; x1[f] = p.y;
  }
  #pragma unroll
  for(int j=0;j<27;j++){
    float bi = bih[t*27+j];
    float a0 = bi, a1 = bi;
    #pragma unroll
    for(int i=0;i<FF;i++){
      float w = Wih[t*243 + i*27 + j];
      a0 += x0[i]*w; a1 += x1[i]*w;
    }
    size_t base = ((size_t)(t*27+j)*BB)*NN + n;
    g_gi[base]      = a0;
    g_gi[base + NN] = a1;
  }
}

// ---- k_gru_seq: h-recurrence only; scalar weights, no LDS ---------------
__global__ void k_gru_seq(const float* __restrict__ g, const float* __restrict__ Whh,
                          const float* __restrict__ bhh, float* __restrict__ out){
  int id = blockIdx.x*128 + threadIdx.x;
  if(id >= BB*NN) return;
  int b = id / NN, n = id - b*NN;
  float c9[FF];
  #pragma unroll
  for(int f=0;f<FF;f++) c9[f] = g_cvec[f];
  float cb = g_cvec[FF+b];
  float h[FF];
  #pragma unroll
  for(int f=0;f<FF;f++) h[f] = 0.f;
  for(int t=0;t<TT;t++){
    float gh[27];
    #pragma unroll
    for(int j=0;j<27;j++) gh[j] = bhh[t*27+j];
    #pragma unroll
    for(int i=0;i<FF;i++){
      float hi = h[i];
      #pragma unroll
      for(int j=0;j<27;j++) gh[j] += hi * Whh[t*243 + i*27 + j];
    }
    float gi[27];
    #pragma unroll
    for(int j=0;j<27;j++)
      gi[j] = g_gi[((size_t)(t*27+j)*BB + b)*NN + n];
    float acc = cb;
    #pragma unroll
    for(int f=0;f<FF;f++){
      float r = 1.f/(1.f+__expf(-(gi[f]+gh[f])));
      float z = 1.f/(1.f+__expf(-(gi[9+f]+gh[9+f])));
      float nv = tanhf(gi[18+f] + r*gh[18+f]);
      h[f] = (1.f-z)*nv + z*h[f];
      acc += h[f]*c9[f];
    }
    size_t gidx = (size_t)(b*TT+t)*NN + n;
    float m = (g[gidx*FF] != 0.f) ? 1.f : 0.f;
    out[gidx] = acc*m;
  }
}

extern "C" void kernel_launch(void* const* d_in, const int* in_sizes, int n_in,
                              void* d_out, int out_size, void* d_ws, size_t ws_size,
                              hipStream_t stream){
  const float* g    = (const float*)d_in[0];
  const float* te   = (const float*)d_in[1];
  const float* ew   = (const float*)d_in[3];
  const int* esrc = (const int*)d_in[4];
  const int* edst = (const int*)d_in[5];
  const float* W1l=(const float*)d_in[6];  const float* b1 =(const float*)d_in[7];  const float* W1r=(const float*)d_in[8];
  const float* W2l=(const float*)d_in[9];  const float* b2 =(const float*)d_in[10]; const float* W2r=(const float*)d_in[11];
  const float* W3l=(const float*)d_in[12]; const float* b3 =(const float*)d_in[13]; const float* W3r=(const float*)d_in[14];
  const float* Wih=(const float*)d_in[15]; const float* Whh=(const float*)d_in[16];
  const float* bih=(const float*)d_in[17]; const float* bhh=(const float*)d_in[18];
  const float* encW=(const float*)d_in[19]; const float* encb=(const float*)d_in[20];
  const float* decW=(const float*)d_in[21]; const float* decb=(const float*)d_in[22];
  float* out = (float*)d_out;

  k_zero <<<(NN+255)/256, 256, 0, stream>>>();
  k_count<<<(EE+255)/256, 256, 0, stream>>>(edst);
  k_scan <<<1, 256, 0, stream>>>();
  k_zero <<<(NN+255)/256, 256, 0, stream>>>();
  k_fill <<<(EE+255)/256, 256, 0, stream>>>(edst, esrc, ew);
  k_head <<<1, 64, 0, stream>>>(encW, encb, decW, decb, te);

  unsigned *p_p, *p_xa, *p_ag, *p_xb;
  hipGetSymbolAddress((void**)&p_p,  HIP_SYMBOL(g_p));
  hipGetSymbolAddress((void**)&p_xa, HIP_SYMBOL(g_xa));
  hipGetSymbolAddress((void**)&p_ag, HIP_SYMBOL(g_ag));
  hipGetSymbolAddress((void**)&p_xb, HIP_SYMBOL(g_xb));

  dim3 ggm((NN+63)/64, TT);
  dim3 gag(1024, TT);                  // t = slow dispatch axis: sliding window
  dim3 ggi((NN+255)/256, TT);
  k_gemm1_all<<<ggm, 256, 0, stream>>>(g, W1l, b1, W1r);
  k_aggt<1><<<gag, 256, 0, stream>>>(p_p, p_xa);     // xa = ELU(agg(P)/deg + Q)
  k_aggt<0><<<gag, 256, 0, stream>>>(p_xa, p_ag);    // ag = agg(xa)/deg
  k_gemm2_all<<<ggm, 256, 0, stream>>>(W2l, b2, W2r);
  k_aggt<0><<<gag, 256, 0, stream>>>(p_xb, p_ag);    // ag = agg(xb)/deg
  k_gemm3_all<<<ggm, 256, 0, stream>>>(W3l, b3, W3r);
  k_gix<<<ggi, 256, 0, stream>>>(Wih, bih);
  k_gru_seq<<<(BB*NN+127)/128, 128, 0, stream>>>(g, Whh, bhh, out);
}